// Round 1
// baseline (144.435 us; speedup 1.0000x reference)
//
#include <hip/hip_runtime.h>

#define N_NODES 4096
#define F_IN 512
#define FHD 64
#define H_HEADS 8
#define C_OUT 512   /* H*FH */
#define ALPHA 0.2f
#define MAXE 512

// ---------------------------------------------------------------------------
// feats[n][h*64+o] = sum_f X[n][f] * W[h][f][o]
// One 4096x512x512 GEMM; each 64-wide column tile is exactly one head.
// ---------------------------------------------------------------------------
__global__ __launch_bounds__(256) void gemm_feats_kernel(
    const float* __restrict__ X, const float* __restrict__ W,
    float* __restrict__ feats) {
  const int h = blockIdx.y;
  const int n0 = blockIdx.x * 64;
  const float* __restrict__ Wh = W + (size_t)h * (F_IN * FHD);
  __shared__ float sX[64][33];  // +1 pad: avoid 4-way conflict on column reads
  __shared__ float sW[32][64];
  const int tid = threadIdx.x;
  const int tr = tid >> 4;   // 0..15
  const int tc = tid & 15;   // 0..15
  float acc[4][4] = {};
  for (int k0 = 0; k0 < F_IN; k0 += 32) {
#pragma unroll
    for (int i = 0; i < 8; ++i) {
      int idx = tid + i * 256;
      int r = idx >> 5, c = idx & 31;
      sX[r][c] = X[(size_t)(n0 + r) * F_IN + k0 + c];
    }
#pragma unroll
    for (int i = 0; i < 8; ++i) {
      int idx = tid + i * 256;
      int r = idx >> 6, c = idx & 63;
      sW[r][c] = Wh[(size_t)(k0 + r) * FHD + c];
    }
    __syncthreads();
#pragma unroll
    for (int kk = 0; kk < 32; ++kk) {
      float a[4], b[4];
#pragma unroll
      for (int i = 0; i < 4; ++i) a[i] = sX[tr * 4 + i][kk];
#pragma unroll
      for (int j = 0; j < 4; ++j) b[j] = sW[kk][tc * 4 + j];
#pragma unroll
      for (int i = 0; i < 4; ++i)
#pragma unroll
        for (int j = 0; j < 4; ++j) acc[i][j] = fmaf(a[i], b[j], acc[i][j]);
    }
    __syncthreads();
  }
#pragma unroll
  for (int i = 0; i < 4; ++i) {
    int row = n0 + tr * 4 + i;
    float4 v = make_float4(acc[i][0], acc[i][1], acc[i][2], acc[i][3]);
    *reinterpret_cast<float4*>(&feats[(size_t)row * C_OUT + h * FHD + tc * 4]) = v;
  }
}

// ---------------------------------------------------------------------------
// s_self[n][h] = feats[n][h*64:..]·a_self[h], same for s_neigh. One wave per (n,h).
// ---------------------------------------------------------------------------
__global__ __launch_bounds__(256) void scores_kernel(
    const float* __restrict__ feats, const float* __restrict__ a_self,
    const float* __restrict__ a_neigh, float* __restrict__ s_self,
    float* __restrict__ s_neigh) {
  const int wid = threadIdx.x >> 6;
  const int lane = threadIdx.x & 63;
  const int wg = blockIdx.x * 4 + wid;  // 0..32767
  const int n = wg >> 3, h = wg & 7;
  float f = feats[(size_t)n * C_OUT + h * FHD + lane];
  float vs = f * a_self[h * FHD + lane];
  float vn = f * a_neigh[h * FHD + lane];
#pragma unroll
  for (int s = 32; s > 0; s >>= 1) {
    vs += __shfl_xor(vs, s, 64);
    vn += __shfl_xor(vn, s, 64);
  }
  if (lane == 0) {
    s_self[n * 8 + h] = vs;
    s_neigh[n * 8 + h] = vn;
  }
}

// ---------------------------------------------------------------------------
// colsum[c] = sum_n feats[n][c], two deterministic stages.
// ---------------------------------------------------------------------------
__global__ __launch_bounds__(512) void colsum_partial_kernel(
    const float* __restrict__ feats, float* __restrict__ partial) {
  const int c = threadIdx.x;
  const int k = blockIdx.x;
  float acc = 0.f;
  for (int r = 0; r < 64; ++r) acc += feats[(size_t)(k * 64 + r) * C_OUT + c];
  partial[k * C_OUT + c] = acc;
}

__global__ __launch_bounds__(512) void colsum_final_kernel(
    const float* __restrict__ partial, float* __restrict__ colsum) {
  const int c = threadIdx.x;
  float acc = 0.f;
  for (int k = 0; k < 64; ++k) acc += partial[k * C_OUT + c];
  colsum[c] = acc;
}

// ---------------------------------------------------------------------------
// One block per row i. Phase 1: deterministic stream-compaction of A's row.
// Phase 2: per-edge per-head LeakyReLU logits. Phase 3: per-head softmax
// stats (max includes the implicit zeros of non-edges). Phase 4: gather-
// accumulate over edges + rank-1 colsum correction, ReLU, store.
// ---------------------------------------------------------------------------
__global__ __launch_bounds__(512) void attn_kernel(
    const float* __restrict__ A, const float* __restrict__ feats,
    const float* __restrict__ s_self, const float* __restrict__ s_neigh,
    const float* __restrict__ colsum, const float* __restrict__ b,
    float* __restrict__ out) {
  const int i = blockIdx.x;
  const int tid = threadIdx.x;
  const int wid = tid >> 6, lane = tid & 63;
  __shared__ int s_idx[MAXE];
  __shared__ float s_w[MAXE][9];  // padded: stride 9 breaks bank aliasing
  __shared__ int s_cnt;
  __shared__ int wave_cnt[8];
  __shared__ float sh_self[8];
  __shared__ float sh_e0[8], sh_invZ[8];

  if (tid == 0) s_cnt = 0;
  if (tid < 8) sh_self[tid] = s_self[i * 8 + tid];
  __syncthreads();

  const float* __restrict__ Arow = A + (size_t)i * N_NODES;
  for (int t = 0; t < N_NODES; t += 512) {
    float a = Arow[t + tid];
    bool p = (a != 0.0f);
    unsigned long long mask = __ballot(p);
    if (lane == 0) wave_cnt[wid] = __popcll(mask);
    int before = __popcll(mask & ((1ULL << lane) - 1ULL));
    __syncthreads();
    int off = s_cnt;
    for (int w = 0; w < wid; ++w) off += wave_cnt[w];
    if (p) {
      int pos = off + before;
      if (pos < MAXE) s_idx[pos] = t + tid;
    }
    __syncthreads();
    if (tid == 0) {
      int tot = 0;
      for (int w = 0; w < 8; ++w) tot += wave_cnt[w];
      s_cnt += tot;
    }
    __syncthreads();
  }
  int deg = s_cnt;
  if (deg > MAXE) deg = MAXE;  // statistically unreachable at p=0.02

  // Phase 2: raw LeakyReLU logits per (edge, head)
  for (int k = tid; k < deg * 8; k += 512) {
    int e = k >> 3, h = k & 7;
    int j = s_idx[e];
    float l = sh_self[h] + s_neigh[j * 8 + h];
    l = l > 0.f ? l : ALPHA * l;
    s_w[e][h] = l;
  }
  __syncthreads();

  // Phase 3: per-head softmax stats; wave `wid` owns head `wid`
  {
    const int h = wid;
    float m = -1e30f;
    for (int e = lane; e < deg; e += 64) m = fmaxf(m, s_w[e][h]);
#pragma unroll
    for (int s = 32; s > 0; s >>= 1) m = fmaxf(m, __shfl_xor(m, s, 64));
    m = fmaxf(m, 0.0f);  // non-edge entries of the dense row are exactly 0
    float e0 = __expf(-m);
    float zs = 0.f;
    for (int e = lane; e < deg; e += 64) {
      float w = __expf(s_w[e][h] - m);
      s_w[e][h] = w - e0;  // edge weight minus the colsum-correction share
      zs += w;
    }
#pragma unroll
    for (int s = 32; s > 0; s >>= 1) zs += __shfl_xor(zs, s, 64);
    if (lane == 0) {
      float Z = zs + (float)(N_NODES - deg) * e0;
      sh_e0[h] = e0;
      sh_invZ[h] = 1.0f / Z;
    }
  }
  __syncthreads();

  // Phase 4: accumulate: thread owns output column c
  const int c = tid;
  const int h = c >> 6;
  float acc = sh_e0[h] * colsum[c];
#pragma unroll 4
  for (int e = 0; e < deg; ++e) {
    acc = fmaf(s_w[e][h], feats[(size_t)s_idx[e] * C_OUT + c], acc);
  }
  float v = acc * sh_invZ[h] + b[c];
  out[(size_t)i * C_OUT + c] = v > 0.f ? v : 0.f;
}

extern "C" void kernel_launch(void* const* d_in, const int* in_sizes, int n_in,
                              void* d_out, int out_size, void* d_ws, size_t ws_size,
                              hipStream_t stream) {
  const float* X = (const float*)d_in[0];
  const float* A = (const float*)d_in[1];
  const float* W = (const float*)d_in[2];
  const float* a_self = (const float*)d_in[3];
  const float* a_neigh = (const float*)d_in[4];
  const float* b = (const float*)d_in[5];
  float* out = (float*)d_out;

  float* ws = (float*)d_ws;
  float* feats = ws;                               // 4096*512
  float* s_self = feats + (size_t)N_NODES * C_OUT; // 4096*8
  float* s_neigh = s_self + N_NODES * H_HEADS;     // 4096*8
  float* partial = s_neigh + N_NODES * H_HEADS;    // 64*512
  float* colsum = partial + 64 * C_OUT;            // 512

  gemm_feats_kernel<<<dim3(64, 8), 256, 0, stream>>>(X, W, feats);
  scores_kernel<<<8192, 256, 0, stream>>>(feats, a_self, a_neigh, s_self, s_neigh);
  colsum_partial_kernel<<<64, 512, 0, stream>>>(feats, partial);
  colsum_final_kernel<<<1, 512, 0, stream>>>(partial, colsum);
  attn_kernel<<<N_NODES, 512, 0, stream>>>(A, feats, s_self, s_neigh, colsum, b, out);
}

// Round 3
// 131.585 us; speedup vs baseline: 1.0977x; 1.0977x over previous
//
#include <hip/hip_runtime.h>
#include <hip/hip_bf16.h>

#define N_NODES 4096
#define F_IN 512
#define FHD 64
#define H_HEADS 8
#define C_OUT 512   /* H*FH */
#define ALPHA 0.2f
#define MAXE 256

static __device__ __forceinline__ unsigned short f2bf(float f) {
  __hip_bfloat16 h = __float2bfloat16(f);
  union { __hip_bfloat16 h; unsigned short u; } cvt;
  cvt.h = h;
  return cvt.u;
}

// ---------------------------------------------------------------------------
// feats[n][h*64+o] = sum_f X[n][f] * W[h][f][o], stored bf16 (f32 accum).
// Fused epilogue: s_self[n][h], s_neigh[n][h] from the in-register acc tile.
// ---------------------------------------------------------------------------
__global__ __launch_bounds__(256) void gemm_feats_kernel(
    const float* __restrict__ X, const float* __restrict__ W,
    const float* __restrict__ a_self, const float* __restrict__ a_neigh,
    __hip_bfloat16* __restrict__ featsb,
    float* __restrict__ s_self, float* __restrict__ s_neigh) {
  const int h = blockIdx.y;
  const int n0 = blockIdx.x * 64;
  const float* __restrict__ Wh = W + (size_t)h * (F_IN * FHD);
  __shared__ float sX[64][33];  // +1 pad: avoid conflicts on column reads
  __shared__ float sW[32][64];
  const int tid = threadIdx.x;
  const int tr = tid >> 4;   // 0..15
  const int tc = tid & 15;   // 0..15
  float acc[4][4] = {};
  for (int k0 = 0; k0 < F_IN; k0 += 32) {
#pragma unroll
    for (int i = 0; i < 8; ++i) {
      int idx = tid + i * 256;
      int r = idx >> 5, c = idx & 31;
      sX[r][c] = X[(size_t)(n0 + r) * F_IN + k0 + c];
    }
#pragma unroll
    for (int i = 0; i < 8; ++i) {
      int idx = tid + i * 256;
      int r = idx >> 6, c = idx & 63;
      sW[r][c] = Wh[(size_t)(k0 + r) * FHD + c];
    }
    __syncthreads();
#pragma unroll
    for (int kk = 0; kk < 32; ++kk) {
      float a[4], b[4];
#pragma unroll
      for (int i = 0; i < 4; ++i) a[i] = sX[tr * 4 + i][kk];
#pragma unroll
      for (int j = 0; j < 4; ++j) b[j] = sW[kk][tc * 4 + j];
#pragma unroll
      for (int i = 0; i < 4; ++i)
#pragma unroll
        for (int j = 0; j < 4; ++j) acc[i][j] = fmaf(a[i], b[j], acc[i][j]);
    }
    __syncthreads();
  }
  // bf16 store
#pragma unroll
  for (int i = 0; i < 4; ++i) {
    int row = n0 + tr * 4 + i;
    ushort4 v;
    v.x = f2bf(acc[i][0]);
    v.y = f2bf(acc[i][1]);
    v.z = f2bf(acc[i][2]);
    v.w = f2bf(acc[i][3]);
    *reinterpret_cast<ushort4*>(&featsb[(size_t)row * C_OUT + h * FHD + tc * 4]) = v;
  }
  // fused scores: reduce across the 16 tc lanes of each tr group
  float as4[4], an4[4];
#pragma unroll
  for (int j = 0; j < 4; ++j) {
    as4[j] = a_self[h * FHD + tc * 4 + j];
    an4[j] = a_neigh[h * FHD + tc * 4 + j];
  }
#pragma unroll
  for (int i = 0; i < 4; ++i) {
    float ps = 0.f, pn = 0.f;
#pragma unroll
    for (int j = 0; j < 4; ++j) {
      ps = fmaf(acc[i][j], as4[j], ps);
      pn = fmaf(acc[i][j], an4[j], pn);
    }
#pragma unroll
    for (int s = 8; s > 0; s >>= 1) {
      ps += __shfl_xor(ps, s, 64);
      pn += __shfl_xor(pn, s, 64);
    }
    if (tc == 0) {
      int row = n0 + tr * 4 + i;
      s_self[row * 8 + h] = ps;
      s_neigh[row * 8 + h] = pn;
    }
  }
}

// ---------------------------------------------------------------------------
// colsum[c] = sum_n feats[n][c], two deterministic stages (bf16 in, f32 accum)
// ---------------------------------------------------------------------------
__global__ __launch_bounds__(512) void colsum_partial_kernel(
    const __hip_bfloat16* __restrict__ featsb, float* __restrict__ partial) {
  const int c = threadIdx.x;
  const int k = blockIdx.x;
  float acc = 0.f;
  for (int r = 0; r < 64; ++r)
    acc += __bfloat162float(featsb[(size_t)(k * 64 + r) * C_OUT + c]);
  partial[k * C_OUT + c] = acc;
}

__global__ __launch_bounds__(512) void colsum_final_kernel(
    const float* __restrict__ partial, float* __restrict__ colsum) {
  const int c = threadIdx.x;
  float acc = 0.f;
  for (int k = 0; k < 64; ++k) acc += partial[k * C_OUT + c];
  colsum[c] = acc;
}

// ---------------------------------------------------------------------------
// One block per row i.
// Phase 1: compaction of A's row via per-thread 8-chunks + wave scan (2 barriers)
// Phase 2: per-(edge,head) LeakyReLU logits
// Phase 3: per-head softmax stats (implicit zeros of non-edges included)
// Phase 4: gather-accumulate (bf16 feats) + rank-1 colsum correction, ReLU.
// ---------------------------------------------------------------------------
__global__ __launch_bounds__(512) void attn_kernel(
    const float* __restrict__ A, const __hip_bfloat16* __restrict__ featsb,
    const float* __restrict__ s_self, const float* __restrict__ s_neigh,
    const float* __restrict__ colsum, const float* __restrict__ bias,
    float* __restrict__ out) {
  const int i = blockIdx.x;
  const int tid = threadIdx.x;
  const int wid = tid >> 6, lane = tid & 63;
  __shared__ int s_idx[MAXE];
  __shared__ float s_w[MAXE][9];  // stride 9 breaks bank aliasing
  __shared__ int wave_tot[8];
  __shared__ float sh_self[8];
  __shared__ float sh_e0[8], sh_invZ[8];

  if (tid < 8) sh_self[tid] = s_self[i * 8 + tid];

  // ---- Phase 1: each thread owns 8 consecutive elements of A's row
  const float4* __restrict__ Arow4 =
      reinterpret_cast<const float4*>(A + (size_t)i * N_NODES);
  float4 v0 = Arow4[tid * 2];
  float4 v1 = Arow4[tid * 2 + 1];
  int mask8 = 0;
  mask8 |= (v0.x != 0.f) ? 1 : 0;
  mask8 |= (v0.y != 0.f) ? 2 : 0;
  mask8 |= (v0.z != 0.f) ? 4 : 0;
  mask8 |= (v0.w != 0.f) ? 8 : 0;
  mask8 |= (v1.x != 0.f) ? 16 : 0;
  mask8 |= (v1.y != 0.f) ? 32 : 0;
  mask8 |= (v1.z != 0.f) ? 64 : 0;
  mask8 |= (v1.w != 0.f) ? 128 : 0;
  int cnt = __popc(mask8);
  int inc = cnt;  // wave-inclusive scan
#pragma unroll
  for (int s = 1; s < 64; s <<= 1) {
    int t = __shfl_up(inc, s, 64);
    if (lane >= s) inc += t;
  }
  if (lane == 63) wave_tot[wid] = inc;
  __syncthreads();
  int wprefix = 0, tot = 0;
#pragma unroll
  for (int w = 0; w < 8; ++w) {
    int t = wave_tot[w];
    if (w < wid) wprefix += t;
    tot += t;
  }
  int pos = wprefix + inc - cnt;
  const int jbase = tid * 8;
  while (mask8) {
    int k = __ffs(mask8) - 1;
    mask8 &= mask8 - 1;
    if (pos < MAXE) s_idx[pos] = jbase + k;
    ++pos;
  }
  const int deg = tot < MAXE ? tot : MAXE;
  __syncthreads();

  // ---- Phase 2: raw LeakyReLU logits per (edge, head)
  for (int k = tid; k < deg * 8; k += 512) {
    int e = k >> 3, h = k & 7;
    int j = s_idx[e];
    float l = sh_self[h] + s_neigh[j * 8 + h];
    s_w[e][h] = l > 0.f ? l : ALPHA * l;
  }
  __syncthreads();

  // ---- Phase 3: per-head softmax stats; wave `wid` owns head `wid`
  {
    const int h = wid;
    float m = -1e30f;
    for (int e = lane; e < deg; e += 64) m = fmaxf(m, s_w[e][h]);
#pragma unroll
    for (int s = 32; s > 0; s >>= 1) m = fmaxf(m, __shfl_xor(m, s, 64));
    m = fmaxf(m, 0.0f);  // non-edge entries of the dense row are exactly 0
    float e0 = __expf(-m);
    float zs = 0.f;
    for (int e = lane; e < deg; e += 64) {
      float w = __expf(s_w[e][h] - m);
      s_w[e][h] = w - e0;  // edge weight minus colsum-correction share
      zs += w;
    }
#pragma unroll
    for (int s = 32; s > 0; s >>= 1) zs += __shfl_xor(zs, s, 64);
    if (lane == 0) {
      float Z = zs + (float)(N_NODES - deg) * e0;
      sh_e0[h] = e0;
      sh_invZ[h] = 1.0f / Z;
    }
  }
  __syncthreads();

  // ---- Phase 4: thread owns output column c; dual accumulators for ILP
  const int c = tid;
  const int h = c >> 6;
  const float e0 = sh_e0[h], invZ = sh_invZ[h];
  float acc0 = e0 * colsum[c], acc1 = 0.f;
  int e = 0;
  for (; e + 1 < deg; e += 2) {
    float f0 = __bfloat162float(featsb[(size_t)s_idx[e] * C_OUT + c]);
    float f1 = __bfloat162float(featsb[(size_t)s_idx[e + 1] * C_OUT + c]);
    acc0 = fmaf(s_w[e][h], f0, acc0);
    acc1 = fmaf(s_w[e + 1][h], f1, acc1);
  }
  if (e < deg)
    acc0 = fmaf(s_w[e][h],
                __bfloat162float(featsb[(size_t)s_idx[e] * C_OUT + c]), acc0);
  float v = (acc0 + acc1) * invZ + bias[c];
  out[(size_t)i * C_OUT + c] = v > 0.f ? v : 0.f;
}

extern "C" void kernel_launch(void* const* d_in, const int* in_sizes, int n_in,
                              void* d_out, int out_size, void* d_ws, size_t ws_size,
                              hipStream_t stream) {
  const float* X = (const float*)d_in[0];
  const float* A = (const float*)d_in[1];
  const float* W = (const float*)d_in[2];
  const float* a_self = (const float*)d_in[3];
  const float* a_neigh = (const float*)d_in[4];
  const float* b = (const float*)d_in[5];
  float* out = (float*)d_out;

  char* ws = (char*)d_ws;
  __hip_bfloat16* featsb = (__hip_bfloat16*)ws;               // 4096*512*2B
  float* s_self = (float*)(ws + (size_t)N_NODES * C_OUT * 2); // 4096*8
  float* s_neigh = s_self + N_NODES * H_HEADS;
  float* partial = s_neigh + N_NODES * H_HEADS;               // 64*512
  float* colsum = partial + 64 * C_OUT;                       // 512

  gemm_feats_kernel<<<dim3(64, 8), 256, 0, stream>>>(X, W, a_self, a_neigh,
                                                     featsb, s_self, s_neigh);
  colsum_partial_kernel<<<64, 512, 0, stream>>>(featsb, partial);
  colsum_final_kernel<<<1, 512, 0, stream>>>(partial, colsum);
  attn_kernel<<<N_NODES, 512, 0, stream>>>(A, featsb, s_self, s_neigh, colsum,
                                           b, out);
}

// Round 4
// 93.347 us; speedup vs baseline: 1.5473x; 1.4096x over previous
//
#include <hip/hip_runtime.h>
#include <hip/hip_bf16.h>

#define N_NODES 4096
#define F_IN 512
#define FHD 64
#define H_HEADS 8
#define C_OUT 512   /* H*FH */
#define ALPHA 0.2f
#define MAXE 192

static __device__ __forceinline__ unsigned short f2bf(float f) {
  __hip_bfloat16 h = __float2bfloat16(f);
  union { __hip_bfloat16 h; unsigned short u; } cvt;
  cvt.h = h;
  return cvt.u;
}
static __device__ __forceinline__ float bf2f(unsigned short u) {
  return __uint_as_float(((unsigned)u) << 16);
}

// ---------------------------------------------------------------------------
// build_csr: pure-streaming compaction of A rows -> u16 edge lists + degs.
// One block (256 thr) per row; each thread owns 16 consecutive elements.
// ---------------------------------------------------------------------------
__global__ __launch_bounds__(256) void build_csr_kernel(
    const float* __restrict__ A, unsigned short* __restrict__ edges,
    int* __restrict__ degs) {
  const int i = blockIdx.x;
  const int tid = threadIdx.x;
  const int wid = tid >> 6, lane = tid & 63;
  __shared__ int wave_tot[4];
  const float4* __restrict__ Arow4 =
      reinterpret_cast<const float4*>(A + (size_t)i * N_NODES);
  float4 v[4];
#pragma unroll
  for (int q = 0; q < 4; ++q) v[q] = Arow4[tid * 4 + q];
  int mask16 = 0;
#pragma unroll
  for (int q = 0; q < 4; ++q) {
    mask16 |= (v[q].x != 0.f) ? (1 << (q * 4 + 0)) : 0;
    mask16 |= (v[q].y != 0.f) ? (1 << (q * 4 + 1)) : 0;
    mask16 |= (v[q].z != 0.f) ? (1 << (q * 4 + 2)) : 0;
    mask16 |= (v[q].w != 0.f) ? (1 << (q * 4 + 3)) : 0;
  }
  int cnt = __popc(mask16);
  int inc = cnt;
#pragma unroll
  for (int s = 1; s < 64; s <<= 1) {
    int t = __shfl_up(inc, s, 64);
    if (lane >= s) inc += t;
  }
  if (lane == 63) wave_tot[wid] = inc;
  __syncthreads();
  int wprefix = 0, tot = 0;
#pragma unroll
  for (int w = 0; w < 4; ++w) {
    int t = wave_tot[w];
    if (w < wid) wprefix += t;
    tot += t;
  }
  int pos = wprefix + inc - cnt;
  const int jbase = tid * 16;
  unsigned short* __restrict__ erow = edges + (size_t)i * MAXE;
  while (mask16) {
    int k = __ffs(mask16) - 1;
    mask16 &= mask16 - 1;
    if (pos < MAXE) erow[pos] = (unsigned short)(jbase + k);
    ++pos;
  }
  if (tid == 0) degs[i] = tot < MAXE ? tot : MAXE;
}

// ---------------------------------------------------------------------------
// feats[n][h*64+o] = sum_f X[n][f] * W[h][f][o], stored bf16 (f32 accum).
// Fused epilogue: s_self[n][h], s_neigh[n][h] from the in-register acc tile.
// ---------------------------------------------------------------------------
__global__ __launch_bounds__(256) void gemm_feats_kernel(
    const float* __restrict__ X, const float* __restrict__ W,
    const float* __restrict__ a_self, const float* __restrict__ a_neigh,
    __hip_bfloat16* __restrict__ featsb,
    float* __restrict__ s_self, float* __restrict__ s_neigh) {
  const int h = blockIdx.y;
  const int n0 = blockIdx.x * 64;
  const float* __restrict__ Wh = W + (size_t)h * (F_IN * FHD);
  __shared__ float sX[64][33];
  __shared__ float sW[32][64];
  const int tid = threadIdx.x;
  const int tr = tid >> 4;
  const int tc = tid & 15;
  float acc[4][4] = {};
  for (int k0 = 0; k0 < F_IN; k0 += 32) {
#pragma unroll
    for (int i = 0; i < 8; ++i) {
      int idx = tid + i * 256;
      int r = idx >> 5, c = idx & 31;
      sX[r][c] = X[(size_t)(n0 + r) * F_IN + k0 + c];
    }
#pragma unroll
    for (int i = 0; i < 8; ++i) {
      int idx = tid + i * 256;
      int r = idx >> 6, c = idx & 63;
      sW[r][c] = Wh[(size_t)(k0 + r) * FHD + c];
    }
    __syncthreads();
#pragma unroll
    for (int kk = 0; kk < 32; ++kk) {
      float a[4], b[4];
#pragma unroll
      for (int i = 0; i < 4; ++i) a[i] = sX[tr * 4 + i][kk];
#pragma unroll
      for (int j = 0; j < 4; ++j) b[j] = sW[kk][tc * 4 + j];
#pragma unroll
      for (int i = 0; i < 4; ++i)
#pragma unroll
        for (int j = 0; j < 4; ++j) acc[i][j] = fmaf(a[i], b[j], acc[i][j]);
    }
    __syncthreads();
  }
#pragma unroll
  for (int i = 0; i < 4; ++i) {
    int row = n0 + tr * 4 + i;
    ushort4 v;
    v.x = f2bf(acc[i][0]);
    v.y = f2bf(acc[i][1]);
    v.z = f2bf(acc[i][2]);
    v.w = f2bf(acc[i][3]);
    *reinterpret_cast<ushort4*>(&featsb[(size_t)row * C_OUT + h * FHD + tc * 4]) = v;
  }
  float as4[4], an4[4];
#pragma unroll
  for (int j = 0; j < 4; ++j) {
    as4[j] = a_self[h * FHD + tc * 4 + j];
    an4[j] = a_neigh[h * FHD + tc * 4 + j];
  }
#pragma unroll
  for (int i = 0; i < 4; ++i) {
    float ps = 0.f, pn = 0.f;
#pragma unroll
    for (int j = 0; j < 4; ++j) {
      ps = fmaf(acc[i][j], as4[j], ps);
      pn = fmaf(acc[i][j], an4[j], pn);
    }
#pragma unroll
    for (int s = 8; s > 0; s >>= 1) {
      ps += __shfl_xor(ps, s, 64);
      pn += __shfl_xor(pn, s, 64);
    }
    if (tc == 0) {
      int row = n0 + tr * 4 + i;
      s_self[row * 8 + h] = ps;
      s_neigh[row * 8 + h] = pn;
    }
  }
}

// ---------------------------------------------------------------------------
// colsum[c] = sum_n feats[n][c] (bf16 in, f32 accum), two stages
// ---------------------------------------------------------------------------
__global__ __launch_bounds__(512) void colsum_partial_kernel(
    const __hip_bfloat16* __restrict__ featsb, float* __restrict__ partial) {
  const int c = threadIdx.x;
  const int k = blockIdx.x;
  float acc = 0.f;
#pragma unroll 4
  for (int r = 0; r < 64; ++r)
    acc += bf2f(((const unsigned short*)featsb)[(size_t)(k * 64 + r) * C_OUT + c]);
  partial[k * C_OUT + c] = acc;
}

__global__ __launch_bounds__(512) void colsum_final_kernel(
    const float* __restrict__ partial, float* __restrict__ colsum) {
  const int c = threadIdx.x;
  float acc = 0.f;
#pragma unroll 4
  for (int k = 0; k < 64; ++k) acc += partial[k * C_OUT + c];
  colsum[c] = acc;
}

// ---------------------------------------------------------------------------
// attn: one block (256 thr) per row i; CSR already built.
// Phase 2: per-(edge,head) LeakyReLU logits
// Phase 3: per-head softmax stats (implicit zeros of non-edges included)
// Phase 4: gather-accumulate (bf16 feats, 2 cols/thread) + colsum correction.
// ---------------------------------------------------------------------------
__global__ __launch_bounds__(256) void attn_kernel(
    const unsigned short* __restrict__ edges, const int* __restrict__ degs,
    const __hip_bfloat16* __restrict__ featsb,
    const float* __restrict__ s_self, const float* __restrict__ s_neigh,
    const float* __restrict__ colsum, const float* __restrict__ bias,
    float* __restrict__ out) {
  const int i = blockIdx.x;
  const int tid = threadIdx.x;
  const int wid = tid >> 6, lane = tid & 63;
  __shared__ int s_idx[MAXE];
  __shared__ float s_w[MAXE][9];
  __shared__ float sh_self[8];
  __shared__ float sh_e0[8], sh_invZ[8];

  const int deg = degs[i];
  if (tid < 8) sh_self[tid] = s_self[i * 8 + tid];
  if (tid < deg) s_idx[tid] = edges[(size_t)i * MAXE + tid];
  __syncthreads();

  // Phase 2: raw LeakyReLU logits per (edge, head)
  for (int k = tid; k < deg * 8; k += 256) {
    int e = k >> 3, h = k & 7;
    int j = s_idx[e];
    float l = sh_self[h] + s_neigh[j * 8 + h];
    s_w[e][h] = l > 0.f ? l : ALPHA * l;
  }
  __syncthreads();

  // Phase 3: wave wid handles heads 2*wid, 2*wid+1
#pragma unroll
  for (int p = 0; p < 2; ++p) {
    const int h = wid * 2 + p;
    float m = -1e30f;
    for (int e = lane; e < deg; e += 64) m = fmaxf(m, s_w[e][h]);
#pragma unroll
    for (int s = 32; s > 0; s >>= 1) m = fmaxf(m, __shfl_xor(m, s, 64));
    m = fmaxf(m, 0.0f);  // non-edge dense entries are exactly 0
    float e0 = __expf(-m);
    float zs = 0.f;
    for (int e = lane; e < deg; e += 64) {
      float w = __expf(s_w[e][h] - m);
      s_w[e][h] = w - e0;  // edge weight minus colsum-correction share
      zs += w;
    }
#pragma unroll
    for (int s = 32; s > 0; s >>= 1) zs += __shfl_xor(zs, s, 64);
    if (lane == 0) {
      sh_e0[h] = e0;
      sh_invZ[h] = 1.0f / (zs + (float)(N_NODES - deg) * e0);
    }
  }
  __syncthreads();

  // Phase 4: thread owns columns (2*tid, 2*tid+1); 4 FMA chains
  const int h = tid >> 5;
  const float e0 = sh_e0[h], invZ = sh_invZ[h];
  const float2 cs = *reinterpret_cast<const float2*>(&colsum[tid * 2]);
  const ushort2* __restrict__ fb = reinterpret_cast<const ushort2*>(featsb);
  float ax0 = e0 * cs.x, ay0 = e0 * cs.y, ax1 = 0.f, ay1 = 0.f;
  int e = 0;
  for (; e + 1 < deg; e += 2) {
    int j0 = s_idx[e], j1 = s_idx[e + 1];
    float w0 = s_w[e][h], w1 = s_w[e + 1][h];
    ushort2 u0 = fb[(size_t)j0 * 256 + tid];
    ushort2 u1 = fb[(size_t)j1 * 256 + tid];
    ax0 = fmaf(w0, bf2f(u0.x), ax0);
    ay0 = fmaf(w0, bf2f(u0.y), ay0);
    ax1 = fmaf(w1, bf2f(u1.x), ax1);
    ay1 = fmaf(w1, bf2f(u1.y), ay1);
  }
  if (e < deg) {
    float w0 = s_w[e][h];
    ushort2 u0 = fb[(size_t)s_idx[e] * 256 + tid];
    ax0 = fmaf(w0, bf2f(u0.x), ax0);
    ay0 = fmaf(w0, bf2f(u0.y), ay0);
  }
  const float2 bb = *reinterpret_cast<const float2*>(&bias[tid * 2]);
  float vx = (ax0 + ax1) * invZ + bb.x;
  float vy = (ay0 + ay1) * invZ + bb.y;
  float2 o;
  o.x = vx > 0.f ? vx : 0.f;
  o.y = vy > 0.f ? vy : 0.f;
  *reinterpret_cast<float2*>(&out[(size_t)i * C_OUT + tid * 2]) = o;
}

extern "C" void kernel_launch(void* const* d_in, const int* in_sizes, int n_in,
                              void* d_out, int out_size, void* d_ws, size_t ws_size,
                              hipStream_t stream) {
  const float* X = (const float*)d_in[0];
  const float* A = (const float*)d_in[1];
  const float* W = (const float*)d_in[2];
  const float* a_self = (const float*)d_in[3];
  const float* a_neigh = (const float*)d_in[4];
  const float* b = (const float*)d_in[5];
  float* out = (float*)d_out;

  char* ws = (char*)d_ws;
  __hip_bfloat16* featsb = (__hip_bfloat16*)ws;               // 4 MB
  char* p = ws + (size_t)N_NODES * C_OUT * 2;
  float* s_self = (float*)p;  p += N_NODES * H_HEADS * 4;     // 128 KB
  float* s_neigh = (float*)p; p += N_NODES * H_HEADS * 4;     // 128 KB
  float* partial = (float*)p; p += 64 * C_OUT * 4;            // 128 KB
  float* colsum = (float*)p;  p += C_OUT * 4;                 // 2 KB
  int* degs = (int*)p;        p += N_NODES * 4;               // 16 KB
  unsigned short* edges = (unsigned short*)p;                 // 1.5 MB

  build_csr_kernel<<<N_NODES, 256, 0, stream>>>(A, edges, degs);
  gemm_feats_kernel<<<dim3(64, 8), 256, 0, stream>>>(X, W, a_self, a_neigh,
                                                     featsb, s_self, s_neigh);
  colsum_partial_kernel<<<64, 512, 0, stream>>>(featsb, partial);
  colsum_final_kernel<<<1, 512, 0, stream>>>(partial, colsum);
  attn_kernel<<<N_NODES, 256, 0, stream>>>(edges, degs, featsb, s_self,
                                           s_neigh, colsum, b, out);
}

// Round 5
// 76.231 us; speedup vs baseline: 1.8947x; 1.2245x over previous
//
#include <hip/hip_runtime.h>
#include <hip/hip_bf16.h>

#define N_NODES 4096
#define F_IN 512
#define FHD 64
#define H_HEADS 8
#define C_OUT 512   /* H*FH */
#define ALPHA 0.2f
#define MAXE 192

typedef __attribute__((ext_vector_type(8))) short bf16x8;
typedef __attribute__((ext_vector_type(4))) float f32x4;

static __device__ __forceinline__ unsigned short f2bf(float f) {
  __hip_bfloat16 h = __float2bfloat16(f);
  union { __hip_bfloat16 h; unsigned short u; } cvt;
  cvt.h = h;
  return cvt.u;
}
static __device__ __forceinline__ float bf2f(unsigned short u) {
  return __uint_as_float(((unsigned)u) << 16);
}

// ---------------------------------------------------------------------------
// convX: X f32 -> Xb bf16 (Xb parked in d_out; attn overwrites d_out later)
// ---------------------------------------------------------------------------
__global__ __launch_bounds__(256) void convX_kernel(
    const float* __restrict__ X, unsigned short* __restrict__ Xb) {
  int idx = blockIdx.x * 256 + threadIdx.x;  // 524288 threads, 4 elems each
  float4 v = reinterpret_cast<const float4*>(X)[idx];
  ushort4 u;
  u.x = f2bf(v.x); u.y = f2bf(v.y); u.z = f2bf(v.z); u.w = f2bf(v.w);
  reinterpret_cast<ushort4*>(Xb)[idx] = u;
}

// ---------------------------------------------------------------------------
// convW: W[h][f][o] f32 -> WbT[h][o][f] bf16 (transpose via LDS)
// grid (8 fblk, 8 h)
// ---------------------------------------------------------------------------
__global__ __launch_bounds__(256) void convW_kernel(
    const float* __restrict__ W, unsigned short* __restrict__ WbT) {
  const int fblk = blockIdx.x, h = blockIdx.y;
  __shared__ float sT[64][65];
  const int tid = threadIdx.x;
#pragma unroll
  for (int i = 0; i < 16; ++i) {
    int idx = tid + i * 256;
    int f = idx >> 6, o = idx & 63;
    sT[f][o] = W[((size_t)h * F_IN + fblk * 64 + f) * FHD + o];
  }
  __syncthreads();
#pragma unroll
  for (int i = 0; i < 16; ++i) {
    int idx = tid + i * 256;
    int o = idx >> 6, f = idx & 63;
    WbT[(size_t)h * FHD * F_IN + (size_t)o * F_IN + fblk * 64 + f] =
        f2bf(sT[f][o]);
  }
}

// ---------------------------------------------------------------------------
// build_csr: streaming compaction of A rows -> u16 edge lists + degs.
// ---------------------------------------------------------------------------
__global__ __launch_bounds__(256) void build_csr_kernel(
    const float* __restrict__ A, unsigned short* __restrict__ edges,
    int* __restrict__ degs) {
  const int i = blockIdx.x;
  const int tid = threadIdx.x;
  const int wid = tid >> 6, lane = tid & 63;
  __shared__ int wave_tot[4];
  const float4* __restrict__ Arow4 =
      reinterpret_cast<const float4*>(A + (size_t)i * N_NODES);
  float4 v[4];
#pragma unroll
  for (int q = 0; q < 4; ++q) v[q] = Arow4[tid * 4 + q];
  int mask16 = 0;
#pragma unroll
  for (int q = 0; q < 4; ++q) {
    mask16 |= (v[q].x != 0.f) ? (1 << (q * 4 + 0)) : 0;
    mask16 |= (v[q].y != 0.f) ? (1 << (q * 4 + 1)) : 0;
    mask16 |= (v[q].z != 0.f) ? (1 << (q * 4 + 2)) : 0;
    mask16 |= (v[q].w != 0.f) ? (1 << (q * 4 + 3)) : 0;
  }
  int cnt = __popc(mask16);
  int inc = cnt;
#pragma unroll
  for (int s = 1; s < 64; s <<= 1) {
    int t = __shfl_up(inc, s, 64);
    if (lane >= s) inc += t;
  }
  if (lane == 63) wave_tot[wid] = inc;
  __syncthreads();
  int wprefix = 0, tot = 0;
#pragma unroll
  for (int w = 0; w < 4; ++w) {
    int t = wave_tot[w];
    if (w < wid) wprefix += t;
    tot += t;
  }
  int pos = wprefix + inc - cnt;
  const int jbase = tid * 16;
  unsigned short* __restrict__ erow = edges + (size_t)i * MAXE;
  while (mask16) {
    int k = __ffs(mask16) - 1;
    mask16 &= mask16 - 1;
    if (pos < MAXE) erow[pos] = (unsigned short)(jbase + k);
    ++pos;
  }
  if (tid == 0) degs[i] = tot < MAXE ? tot : MAXE;
}

// ---------------------------------------------------------------------------
// MFMA GEMM: feats[n][h*64+o] = sum_f Xb[n][f] * W[h][f][o], bf16 in/out,
// f32 accum. Fused epilogue: s_self/s_neigh. Block = 128 rows x 1 head,
// 4 waves x (32 rows x 64 cols), K double-buffered.
// A frag: row=l&15, k=(l>>4)*8+j ; B frag: col=l&15, k=(l>>4)*8+j
// C/D:    col=l&15, row=(l>>4)*4+reg   [m89/m91-verified]
// ---------------------------------------------------------------------------
__global__ __launch_bounds__(256) void gemm_feats_mfma_kernel(
    const unsigned short* __restrict__ Xb, const unsigned short* __restrict__ WbT,
    const float* __restrict__ a_self, const float* __restrict__ a_neigh,
    unsigned short* __restrict__ featsb,
    float* __restrict__ s_self, float* __restrict__ s_neigh) {
  const int h = blockIdx.y;
  const int n0 = blockIdx.x * 128;
  __shared__ unsigned short sX[2][128 * 40];  // rows padded 32->40 bf16
  __shared__ unsigned short sW[2][64 * 40];
  const int tid = threadIdx.x;
  const int wid = tid >> 6, lane = tid & 63;
  const int l15 = lane & 15, l4 = lane >> 4;

  // staging: X tile 128x32 (2 thr/row, 2x16B each), W tile 64 cols x 32 k
  const int xrow = tid >> 1, xoff = (tid & 1) * 16;
  const unsigned short* xsrc = Xb + (size_t)(n0 + xrow) * F_IN + xoff;
  const int sxoff = xrow * 40 + xoff;
  const int wn = tid >> 2, woff = (tid & 3) * 8;
  const unsigned short* wsrc = WbT + ((size_t)h * FHD + wn) * F_IN + woff;
  const int swoff = wn * 40 + woff;

  f32x4 acc[2][4];
#pragma unroll
  for (int i = 0; i < 2; ++i)
#pragma unroll
    for (int j = 0; j < 4; ++j) acc[i][j] = (f32x4){0.f, 0.f, 0.f, 0.f};

  // prologue: stage K-step 0 into buf 0
  {
    bf16x8 x0 = *(const bf16x8*)(xsrc);
    bf16x8 x1 = *(const bf16x8*)(xsrc + 8);
    bf16x8 w0 = *(const bf16x8*)(wsrc);
    *(bf16x8*)&sX[0][sxoff] = x0;
    *(bf16x8*)&sX[0][sxoff + 8] = x1;
    *(bf16x8*)&sW[0][swoff] = w0;
  }
  __syncthreads();

  const int arow0 = (wid * 32 + l15) * 40 + l4 * 8;
  const int arow1 = (wid * 32 + 16 + l15) * 40 + l4 * 8;
  int cur = 0;
  for (int s = 0; s < 16; ++s) {
    bf16x8 px0, px1, pw0;
    const bool pf = (s < 15);
    if (pf) {
      const int k = (s + 1) * 32;
      px0 = *(const bf16x8*)(xsrc + k);
      px1 = *(const bf16x8*)(xsrc + k + 8);
      pw0 = *(const bf16x8*)(wsrc + k);
    }
    bf16x8 a0 = *(const bf16x8*)&sX[cur][arow0];
    bf16x8 a1 = *(const bf16x8*)&sX[cur][arow1];
#pragma unroll
    for (int tn = 0; tn < 4; ++tn) {
      bf16x8 b = *(const bf16x8*)&sW[cur][(tn * 16 + l15) * 40 + l4 * 8];
      acc[0][tn] =
          __builtin_amdgcn_mfma_f32_16x16x32_bf16(a0, b, acc[0][tn], 0, 0, 0);
      acc[1][tn] =
          __builtin_amdgcn_mfma_f32_16x16x32_bf16(a1, b, acc[1][tn], 0, 0, 0);
    }
    if (pf) {
      *(bf16x8*)&sX[cur ^ 1][sxoff] = px0;
      *(bf16x8*)&sX[cur ^ 1][sxoff + 8] = px1;
      *(bf16x8*)&sW[cur ^ 1][swoff] = pw0;
      __syncthreads();
      cur ^= 1;
    }
  }

  // epilogue: bf16 feats stores + fused score dot-products
  float aS[4], aN[4];
#pragma unroll
  for (int tn = 0; tn < 4; ++tn) {
    aS[tn] = a_self[h * FHD + tn * 16 + l15];
    aN[tn] = a_neigh[h * FHD + tn * 16 + l15];
  }
#pragma unroll
  for (int tm = 0; tm < 2; ++tm) {
#pragma unroll
    for (int r = 0; r < 4; ++r) {
      const int grow = n0 + wid * 32 + tm * 16 + l4 * 4 + r;
#pragma unroll
      for (int tn = 0; tn < 4; ++tn)
        featsb[(size_t)grow * C_OUT + h * FHD + tn * 16 + l15] =
            f2bf(acc[tm][tn][r]);
      float ps = 0.f, pn = 0.f;
#pragma unroll
      for (int tn = 0; tn < 4; ++tn) {
        float v = acc[tm][tn][r];
        ps = fmaf(v, aS[tn], ps);
        pn = fmaf(v, aN[tn], pn);
      }
#pragma unroll
      for (int sh = 1; sh < 16; sh <<= 1) {
        ps += __shfl_xor(ps, sh, 64);
        pn += __shfl_xor(pn, sh, 64);
      }
      if (l15 == 0) {
        s_self[grow * 8 + h] = ps;
        s_neigh[grow * 8 + h] = pn;
      }
    }
  }
}

// ---------------------------------------------------------------------------
// colsum[c] = sum_n feats[n][c] (bf16 in, f32 accum), two stages
// ---------------------------------------------------------------------------
__global__ __launch_bounds__(512) void colsum_partial_kernel(
    const unsigned short* __restrict__ featsb, float* __restrict__ partial) {
  const int c = threadIdx.x;
  const int k = blockIdx.x;
  float acc = 0.f;
#pragma unroll 4
  for (int r = 0; r < 64; ++r)
    acc += bf2f(featsb[(size_t)(k * 64 + r) * C_OUT + c]);
  partial[k * C_OUT + c] = acc;
}

__global__ __launch_bounds__(512) void colsum_final_kernel(
    const float* __restrict__ partial, float* __restrict__ colsum) {
  const int c = threadIdx.x;
  float acc = 0.f;
#pragma unroll 4
  for (int k = 0; k < 64; ++k) acc += partial[k * C_OUT + c];
  colsum[c] = acc;
}

// ---------------------------------------------------------------------------
// attn: one block (256 thr) per row i; CSR already built.
// ---------------------------------------------------------------------------
__global__ __launch_bounds__(256) void attn_kernel(
    const unsigned short* __restrict__ edges, const int* __restrict__ degs,
    const unsigned short* __restrict__ featsb,
    const float* __restrict__ s_self, const float* __restrict__ s_neigh,
    const float* __restrict__ colsum, const float* __restrict__ bias,
    float* __restrict__ out) {
  const int i = blockIdx.x;
  const int tid = threadIdx.x;
  const int wid = tid >> 6, lane = tid & 63;
  __shared__ int s_idx[MAXE];
  __shared__ float s_w[MAXE][9];
  __shared__ float sh_self[8];
  __shared__ float sh_e0[8], sh_invZ[8];

  const int deg = degs[i];
  if (tid < 8) sh_self[tid] = s_self[i * 8 + tid];
  if (tid < deg) s_idx[tid] = edges[(size_t)i * MAXE + tid];
  __syncthreads();

  for (int k = tid; k < deg * 8; k += 256) {
    int e = k >> 3, h = k & 7;
    int j = s_idx[e];
    float l = sh_self[h] + s_neigh[j * 8 + h];
    s_w[e][h] = l > 0.f ? l : ALPHA * l;
  }
  __syncthreads();

#pragma unroll
  for (int p = 0; p < 2; ++p) {
    const int h = wid * 2 + p;
    float m = -1e30f;
    for (int e = lane; e < deg; e += 64) m = fmaxf(m, s_w[e][h]);
#pragma unroll
    for (int s = 32; s > 0; s >>= 1) m = fmaxf(m, __shfl_xor(m, s, 64));
    m = fmaxf(m, 0.0f);  // non-edge dense entries are exactly 0
    float e0 = __expf(-m);
    float zs = 0.f;
    for (int e = lane; e < deg; e += 64) {
      float w = __expf(s_w[e][h] - m);
      s_w[e][h] = w - e0;  // edge weight minus colsum-correction share
      zs += w;
    }
#pragma unroll
    for (int s = 32; s > 0; s >>= 1) zs += __shfl_xor(zs, s, 64);
    if (lane == 0) {
      sh_e0[h] = e0;
      sh_invZ[h] = 1.0f / (zs + (float)(N_NODES - deg) * e0);
    }
  }
  __syncthreads();

  const int h = tid >> 5;
  const float e0 = sh_e0[h], invZ = sh_invZ[h];
  const float2 cs = *reinterpret_cast<const float2*>(&colsum[tid * 2]);
  const ushort2* __restrict__ fb = reinterpret_cast<const ushort2*>(featsb);
  float ax0 = e0 * cs.x, ay0 = e0 * cs.y, ax1 = 0.f, ay1 = 0.f;
  int e = 0;
  for (; e + 1 < deg; e += 2) {
    int j0 = s_idx[e], j1 = s_idx[e + 1];
    float w0 = s_w[e][h], w1 = s_w[e + 1][h];
    ushort2 u0 = fb[(size_t)j0 * 256 + tid];
    ushort2 u1 = fb[(size_t)j1 * 256 + tid];
    ax0 = fmaf(w0, bf2f(u0.x), ax0);
    ay0 = fmaf(w0, bf2f(u0.y), ay0);
    ax1 = fmaf(w1, bf2f(u1.x), ax1);
    ay1 = fmaf(w1, bf2f(u1.y), ay1);
  }
  if (e < deg) {
    float w0 = s_w[e][h];
    ushort2 u0 = fb[(size_t)s_idx[e] * 256 + tid];
    ax0 = fmaf(w0, bf2f(u0.x), ax0);
    ay0 = fmaf(w0, bf2f(u0.y), ay0);
  }
  const float2 bb = *reinterpret_cast<const float2*>(&bias[tid * 2]);
  float vx = (ax0 + ax1) * invZ + bb.x;
  float vy = (ay0 + ay1) * invZ + bb.y;
  float2 o;
  o.x = vx > 0.f ? vx : 0.f;
  o.y = vy > 0.f ? vy : 0.f;
  *reinterpret_cast<float2*>(&out[(size_t)i * C_OUT + tid * 2]) = o;
}

extern "C" void kernel_launch(void* const* d_in, const int* in_sizes, int n_in,
                              void* d_out, int out_size, void* d_ws, size_t ws_size,
                              hipStream_t stream) {
  const float* X = (const float*)d_in[0];
  const float* A = (const float*)d_in[1];
  const float* W = (const float*)d_in[2];
  const float* a_self = (const float*)d_in[3];
  const float* a_neigh = (const float*)d_in[4];
  const float* b = (const float*)d_in[5];
  float* out = (float*)d_out;

  char* ws = (char*)d_ws;
  unsigned short* featsb = (unsigned short*)ws;               // 4 MB
  char* p = ws + (size_t)N_NODES * C_OUT * 2;
  float* s_self = (float*)p;  p += N_NODES * H_HEADS * 4;     // 128 KB
  float* s_neigh = (float*)p; p += N_NODES * H_HEADS * 4;     // 128 KB
  float* partial = (float*)p; p += 64 * C_OUT * 4;            // 128 KB
  float* colsum = (float*)p;  p += C_OUT * 4;                 // 2 KB
  int* degs = (int*)p;        p += N_NODES * 4;               // 16 KB
  unsigned short* edges = (unsigned short*)p;
  p += (size_t)N_NODES * MAXE * 2;                            // 1.5 MB
  unsigned short* WbT = (unsigned short*)p;                   // 512 KB

  // Xb parked in d_out (4 MB of its 8 MB); attn fully overwrites d_out later.
  unsigned short* Xb = (unsigned short*)d_out;

  convX_kernel<<<2048, 256, 0, stream>>>(X, Xb);
  convW_kernel<<<dim3(8, 8), 256, 0, stream>>>(W, WbT);
  build_csr_kernel<<<N_NODES, 256, 0, stream>>>(A, edges, degs);
  gemm_feats_mfma_kernel<<<dim3(32, 8), 256, 0, stream>>>(
      Xb, WbT, a_self, a_neigh, featsb, s_self, s_neigh);
  colsum_partial_kernel<<<64, 512, 0, stream>>>(featsb, partial);
  colsum_final_kernel<<<1, 512, 0, stream>>>(partial, colsum);
  attn_kernel<<<N_NODES, 256, 0, stream>>>(edges, degs, featsb, s_self,
                                           s_neigh, colsum, b, out);
}

// Round 6
// 59.136 us; speedup vs baseline: 2.4424x; 1.2891x over previous
//
#include <hip/hip_runtime.h>
#include <hip/hip_bf16.h>

#define N_NODES 4096
#define F_IN 512
#define FHD 64
#define H_HEADS 8
#define C_OUT 512   /* H*FH */
#define ALPHA 0.2f
#define MAXE 192

typedef __attribute__((ext_vector_type(8))) short bf16x8;
typedef __attribute__((ext_vector_type(4))) float f32x4;

static __device__ __forceinline__ unsigned short f2bf(float f) {
  __hip_bfloat16 h = __float2bfloat16(f);
  union { __hip_bfloat16 h; unsigned short u; } cvt;
  cvt.h = h;
  return cvt.u;
}
static __device__ __forceinline__ float bf2f(unsigned short u) {
  return __uint_as_float(((unsigned)u) << 16);
}

// ---------------------------------------------------------------------------
// prep: blocks [0,4096) CSR-build | [4096,6144) X->bf16 | [6144,6208) W
// transpose->bf16 | 6208 zero colsum. One launch, all independent streams.
// ---------------------------------------------------------------------------
__global__ __launch_bounds__(256) void prep_kernel(
    const float* __restrict__ A, const float* __restrict__ X,
    const float* __restrict__ W, unsigned short* __restrict__ edges,
    int* __restrict__ degs, unsigned short* __restrict__ Xb,
    unsigned short* __restrict__ WbT, float* __restrict__ colsum) {
  __shared__ int wave_tot[4];
  __shared__ float sT[64][65];
  const int bid = blockIdx.x;
  const int tid = threadIdx.x;

  if (bid < N_NODES) {
    // ---- CSR build: each thread owns 16 consecutive elements of A's row
    const int i = bid;
    const int wid = tid >> 6, lane = tid & 63;
    const float4* __restrict__ Arow4 =
        reinterpret_cast<const float4*>(A + (size_t)i * N_NODES);
    float4 v[4];
#pragma unroll
    for (int q = 0; q < 4; ++q) v[q] = Arow4[tid * 4 + q];
    int mask16 = 0;
#pragma unroll
    for (int q = 0; q < 4; ++q) {
      mask16 |= (v[q].x != 0.f) ? (1 << (q * 4 + 0)) : 0;
      mask16 |= (v[q].y != 0.f) ? (1 << (q * 4 + 1)) : 0;
      mask16 |= (v[q].z != 0.f) ? (1 << (q * 4 + 2)) : 0;
      mask16 |= (v[q].w != 0.f) ? (1 << (q * 4 + 3)) : 0;
    }
    int cnt = __popc(mask16);
    int inc = cnt;
#pragma unroll
    for (int s = 1; s < 64; s <<= 1) {
      int t = __shfl_up(inc, s, 64);
      if (lane >= s) inc += t;
    }
    if (lane == 63) wave_tot[wid] = inc;
    __syncthreads();
    int wprefix = 0, tot = 0;
#pragma unroll
    for (int w = 0; w < 4; ++w) {
      int t = wave_tot[w];
      if (w < wid) wprefix += t;
      tot += t;
    }
    int pos = wprefix + inc - cnt;
    const int jbase = tid * 16;
    unsigned short* __restrict__ erow = edges + (size_t)i * MAXE;
    while (mask16) {
      int k = __ffs(mask16) - 1;
      mask16 &= mask16 - 1;
      if (pos < MAXE) erow[pos] = (unsigned short)(jbase + k);
      ++pos;
    }
    if (tid == 0) degs[i] = tot < MAXE ? tot : MAXE;
  } else if (bid < N_NODES + 2048) {
    // ---- convX: f32 -> bf16, 4 elems/thread
    int idx = (bid - N_NODES) * 256 + tid;
    float4 v = reinterpret_cast<const float4*>(X)[idx];
    ushort4 u;
    u.x = f2bf(v.x); u.y = f2bf(v.y); u.z = f2bf(v.z); u.w = f2bf(v.w);
    reinterpret_cast<ushort4*>(Xb)[idx] = u;
  } else if (bid < N_NODES + 2048 + 64) {
    // ---- convW: W[h][f][o] f32 -> WbT[h][o][f] bf16
    const int b2 = bid - (N_NODES + 2048);
    const int fblk = b2 & 7, h = b2 >> 3;
#pragma unroll
    for (int i = 0; i < 16; ++i) {
      int idx = tid + i * 256;
      int f = idx >> 6, o = idx & 63;
      sT[f][o] = W[((size_t)h * F_IN + fblk * 64 + f) * FHD + o];
    }
    __syncthreads();
#pragma unroll
    for (int i = 0; i < 16; ++i) {
      int idx = tid + i * 256;
      int o = idx >> 6, f = idx & 63;
      WbT[(size_t)h * FHD * F_IN + (size_t)o * F_IN + fblk * 64 + f] =
          f2bf(sT[f][o]);
    }
  } else {
    // ---- zero colsum (gemm accumulates into it atomically)
    colsum[tid] = 0.f;
    colsum[tid + 256] = 0.f;
  }
}

// ---------------------------------------------------------------------------
// MFMA GEMM: feats[n][h*64+o] = sum_f Xb[n][f] * W[h][f][o], bf16 in/out,
// f32 accum. Fused: s_self/s_neigh scores + colsum partial (atomicAdd).
// Block = 128 rows x 1 head, 4 waves x (32 rows x 64 cols), K dbuf.
// A frag: row=l&15, k=(l>>4)*8+j ; B frag: col=l&15, k=(l>>4)*8+j
// C/D:    col=l&15, row=(l>>4)*4+reg   [m89/m91-verified]
// ---------------------------------------------------------------------------
__global__ __launch_bounds__(256) void gemm_feats_mfma_kernel(
    const unsigned short* __restrict__ Xb, const unsigned short* __restrict__ WbT,
    const float* __restrict__ a_self, const float* __restrict__ a_neigh,
    unsigned short* __restrict__ featsb,
    float* __restrict__ s_self, float* __restrict__ s_neigh,
    float* __restrict__ colsum) {
  const int h = blockIdx.y;
  const int n0 = blockIdx.x * 128;
  __shared__ unsigned short sX[2][128 * 40];  // rows padded 32->40 bf16
  __shared__ unsigned short sW[2][64 * 40];
  __shared__ float sred[4][64];
  const int tid = threadIdx.x;
  const int wid = tid >> 6, lane = tid & 63;
  const int l15 = lane & 15, l4 = lane >> 4;

  const int xrow = tid >> 1, xoff = (tid & 1) * 16;
  const unsigned short* xsrc = Xb + (size_t)(n0 + xrow) * F_IN + xoff;
  const int sxoff = xrow * 40 + xoff;
  const int wn = tid >> 2, woff = (tid & 3) * 8;
  const unsigned short* wsrc = WbT + ((size_t)h * FHD + wn) * F_IN + woff;
  const int swoff = wn * 40 + woff;

  f32x4 acc[2][4];
#pragma unroll
  for (int i = 0; i < 2; ++i)
#pragma unroll
    for (int j = 0; j < 4; ++j) acc[i][j] = (f32x4){0.f, 0.f, 0.f, 0.f};

  {
    bf16x8 x0 = *(const bf16x8*)(xsrc);
    bf16x8 x1 = *(const bf16x8*)(xsrc + 8);
    bf16x8 w0 = *(const bf16x8*)(wsrc);
    *(bf16x8*)&sX[0][sxoff] = x0;
    *(bf16x8*)&sX[0][sxoff + 8] = x1;
    *(bf16x8*)&sW[0][swoff] = w0;
  }
  __syncthreads();

  const int arow0 = (wid * 32 + l15) * 40 + l4 * 8;
  const int arow1 = (wid * 32 + 16 + l15) * 40 + l4 * 8;
  int cur = 0;
  for (int s = 0; s < 16; ++s) {
    bf16x8 px0, px1, pw0;
    const bool pf = (s < 15);
    if (pf) {
      const int k = (s + 1) * 32;
      px0 = *(const bf16x8*)(xsrc + k);
      px1 = *(const bf16x8*)(xsrc + k + 8);
      pw0 = *(const bf16x8*)(wsrc + k);
    }
    bf16x8 a0 = *(const bf16x8*)&sX[cur][arow0];
    bf16x8 a1 = *(const bf16x8*)&sX[cur][arow1];
#pragma unroll
    for (int tn = 0; tn < 4; ++tn) {
      bf16x8 b = *(const bf16x8*)&sW[cur][(tn * 16 + l15) * 40 + l4 * 8];
      acc[0][tn] =
          __builtin_amdgcn_mfma_f32_16x16x32_bf16(a0, b, acc[0][tn], 0, 0, 0);
      acc[1][tn] =
          __builtin_amdgcn_mfma_f32_16x16x32_bf16(a1, b, acc[1][tn], 0, 0, 0);
    }
    if (pf) {
      *(bf16x8*)&sX[cur ^ 1][sxoff] = px0;
      *(bf16x8*)&sX[cur ^ 1][sxoff + 8] = px1;
      *(bf16x8*)&sW[cur ^ 1][swoff] = pw0;
      __syncthreads();
      cur ^= 1;
    }
  }

  // epilogue: bf16 feats stores + fused score dot-products
  float aS[4], aN[4];
#pragma unroll
  for (int tn = 0; tn < 4; ++tn) {
    aS[tn] = a_self[h * FHD + tn * 16 + l15];
    aN[tn] = a_neigh[h * FHD + tn * 16 + l15];
  }
#pragma unroll
  for (int tm = 0; tm < 2; ++tm) {
#pragma unroll
    for (int r = 0; r < 4; ++r) {
      const int grow = n0 + wid * 32 + tm * 16 + l4 * 4 + r;
#pragma unroll
      for (int tn = 0; tn < 4; ++tn)
        featsb[(size_t)grow * C_OUT + h * FHD + tn * 16 + l15] =
            f2bf(acc[tm][tn][r]);
      float ps = 0.f, pn = 0.f;
#pragma unroll
      for (int tn = 0; tn < 4; ++tn) {
        float v = acc[tm][tn][r];
        ps = fmaf(v, aS[tn], ps);
        pn = fmaf(v, aN[tn], pn);
      }
#pragma unroll
      for (int sh = 1; sh < 16; sh <<= 1) {
        ps += __shfl_xor(ps, sh, 64);
        pn += __shfl_xor(pn, sh, 64);
      }
      if (l15 == 0) {
        s_self[grow * 8 + h] = ps;
        s_neigh[grow * 8 + h] = pn;
      }
    }
  }

  // fused colsum partial: per-thread sum over tm,r; shfl over l4 groups;
  // cross-wave via LDS; 64 atomicAdds per block.
  float psum[4];
#pragma unroll
  for (int tn = 0; tn < 4; ++tn) {
    float s = 0.f;
#pragma unroll
    for (int tm = 0; tm < 2; ++tm)
#pragma unroll
      for (int r = 0; r < 4; ++r) s += acc[tm][tn][r];
    s += __shfl_xor(s, 16, 64);
    s += __shfl_xor(s, 32, 64);
    psum[tn] = s;
  }
  if (l4 == 0) {
#pragma unroll
    for (int tn = 0; tn < 4; ++tn) sred[wid][tn * 16 + l15] = psum[tn];
  }
  __syncthreads();
  if (tid < 64) {
    float s = sred[0][tid] + sred[1][tid] + sred[2][tid] + sred[3][tid];
    atomicAdd(&colsum[h * FHD + tid], s);
  }
}

// ---------------------------------------------------------------------------
// attn: one block (256 thr) per row i; CSR pre-built, colsum pre-summed.
// ---------------------------------------------------------------------------
__global__ __launch_bounds__(256) void attn_kernel(
    const unsigned short* __restrict__ edges, const int* __restrict__ degs,
    const unsigned short* __restrict__ featsb,
    const float* __restrict__ s_self, const float* __restrict__ s_neigh,
    const float* __restrict__ colsum, const float* __restrict__ bias,
    float* __restrict__ out) {
  const int i = blockIdx.x;
  const int tid = threadIdx.x;
  const int wid = tid >> 6, lane = tid & 63;
  __shared__ int s_idx[MAXE];
  __shared__ float s_w[MAXE][9];
  __shared__ float sh_self[8];
  __shared__ float sh_e0[8], sh_invZ[8];

  const int deg = degs[i];
  if (tid < 8) sh_self[tid] = s_self[i * 8 + tid];
  if (tid < deg) s_idx[tid] = edges[(size_t)i * MAXE + tid];
  __syncthreads();

  for (int k = tid; k < deg * 8; k += 256) {
    int e = k >> 3, h = k & 7;
    int j = s_idx[e];
    float l = sh_self[h] + s_neigh[j * 8 + h];
    s_w[e][h] = l > 0.f ? l : ALPHA * l;
  }
  __syncthreads();

#pragma unroll
  for (int p = 0; p < 2; ++p) {
    const int h = wid * 2 + p;
    float m = -1e30f;
    for (int e = lane; e < deg; e += 64) m = fmaxf(m, s_w[e][h]);
#pragma unroll
    for (int s = 32; s > 0; s >>= 1) m = fmaxf(m, __shfl_xor(m, s, 64));
    m = fmaxf(m, 0.0f);  // non-edge dense entries are exactly 0
    float e0 = __expf(-m);
    float zs = 0.f;
    for (int e = lane; e < deg; e += 64) {
      float w = __expf(s_w[e][h] - m);
      s_w[e][h] = w - e0;  // edge weight minus colsum-correction share
      zs += w;
    }
#pragma unroll
    for (int s = 32; s > 0; s >>= 1) zs += __shfl_xor(zs, s, 64);
    if (lane == 0) {
      sh_e0[h] = e0;
      sh_invZ[h] = 1.0f / (zs + (float)(N_NODES - deg) * e0);
    }
  }
  __syncthreads();

  // Phase 4: thread owns columns (2*tid, 2*tid+1); 8 FMA chains, unroll 4
  const int h = tid >> 5;
  const float e0 = sh_e0[h], invZ = sh_invZ[h];
  const float2 cs = *reinterpret_cast<const float2*>(&colsum[tid * 2]);
  const ushort2* __restrict__ fb = reinterpret_cast<const ushort2*>(featsb);
  float ax0 = e0 * cs.x, ay0 = e0 * cs.y;
  float ax1 = 0.f, ay1 = 0.f, ax2 = 0.f, ay2 = 0.f, ax3 = 0.f, ay3 = 0.f;
  int e = 0;
  for (; e + 3 < deg; e += 4) {
    int j0 = s_idx[e], j1 = s_idx[e + 1], j2 = s_idx[e + 2], j3 = s_idx[e + 3];
    float w0 = s_w[e][h], w1 = s_w[e + 1][h];
    float w2 = s_w[e + 2][h], w3 = s_w[e + 3][h];
    ushort2 u0 = fb[(size_t)j0 * 256 + tid];
    ushort2 u1 = fb[(size_t)j1 * 256 + tid];
    ushort2 u2 = fb[(size_t)j2 * 256 + tid];
    ushort2 u3 = fb[(size_t)j3 * 256 + tid];
    ax0 = fmaf(w0, bf2f(u0.x), ax0);
    ay0 = fmaf(w0, bf2f(u0.y), ay0);
    ax1 = fmaf(w1, bf2f(u1.x), ax1);
    ay1 = fmaf(w1, bf2f(u1.y), ay1);
    ax2 = fmaf(w2, bf2f(u2.x), ax2);
    ay2 = fmaf(w2, bf2f(u2.y), ay2);
    ax3 = fmaf(w3, bf2f(u3.x), ax3);
    ay3 = fmaf(w3, bf2f(u3.y), ay3);
  }
  for (; e < deg; ++e) {
    float w0 = s_w[e][h];
    ushort2 u0 = fb[(size_t)s_idx[e] * 256 + tid];
    ax0 = fmaf(w0, bf2f(u0.x), ax0);
    ay0 = fmaf(w0, bf2f(u0.y), ay0);
  }
  const float2 bb = *reinterpret_cast<const float2*>(&bias[tid * 2]);
  float vx = ((ax0 + ax1) + (ax2 + ax3)) * invZ + bb.x;
  float vy = ((ay0 + ay1) + (ay2 + ay3)) * invZ + bb.y;
  float2 o;
  o.x = vx > 0.f ? vx : 0.f;
  o.y = vy > 0.f ? vy : 0.f;
  *reinterpret_cast<float2*>(&out[(size_t)i * C_OUT + tid * 2]) = o;
}

extern "C" void kernel_launch(void* const* d_in, const int* in_sizes, int n_in,
                              void* d_out, int out_size, void* d_ws, size_t ws_size,
                              hipStream_t stream) {
  const float* X = (const float*)d_in[0];
  const float* A = (const float*)d_in[1];
  const float* W = (const float*)d_in[2];
  const float* a_self = (const float*)d_in[3];
  const float* a_neigh = (const float*)d_in[4];
  const float* b = (const float*)d_in[5];
  float* out = (float*)d_out;

  char* ws = (char*)d_ws;
  unsigned short* featsb = (unsigned short*)ws;               // 4 MB
  char* p = ws + (size_t)N_NODES * C_OUT * 2;
  float* s_self = (float*)p;  p += N_NODES * H_HEADS * 4;     // 128 KB
  float* s_neigh = (float*)p; p += N_NODES * H_HEADS * 4;     // 128 KB
  float* colsum = (float*)p;  p += C_OUT * 4;                 // 2 KB
  int* degs = (int*)p;        p += N_NODES * 4;               // 16 KB
  unsigned short* edges = (unsigned short*)p;
  p += (size_t)N_NODES * MAXE * 2;                            // 1.5 MB
  unsigned short* WbT = (unsigned short*)p;                   // 512 KB

  // Xb parked in d_out (4 MB of its 8 MB); attn fully overwrites d_out later.
  unsigned short* Xb = (unsigned short*)d_out;

  prep_kernel<<<N_NODES + 2048 + 64 + 1, 256, 0, stream>>>(
      A, X, W, edges, degs, Xb, WbT, colsum);
  gemm_feats_mfma_kernel<<<dim3(32, 8), 256, 0, stream>>>(
      Xb, WbT, a_self, a_neigh, featsb, s_self, s_neigh, colsum);
  attn_kernel<<<N_NODES, 256, 0, stream>>>(edges, degs, featsb, s_self,
                                           s_neigh, colsum, b, out);
}